// Round 13
// baseline (424.109 us; speedup 1.0000x reference)
//
#include <hip/hip_runtime.h>
#include <hip/hip_bf16.h>

// LGA3D2: out = A_g(A_g(x)); A_g is a 5x5 spatial x 3-depth guided aggregation.
// out[b,c,d,h,w] = sum_{i,j in 5x5, k in 0..2} g[b,(i*5+j)*3+k,h,w] * x[b,c,d+k-1,h+i-2,w+j-2]
// x: [B,C,D,H,W] fp32, g: [B,75,H,W] fp32.
//
// R13 = R12 (f16 LDS slabs + v_dot2_f32_f16, g j-pairs staged in LDS,
// reg-staged x, dbuf across i-taps) with the STAGE ORDER fixed (T14):
// R12 issued xstage_load then immediately __syncthreads() -> the barrier's
// mandatory vmcnt(0) drained the HBM loads with no compute in between, and
// gstage's fused load->ds_write forced a second drain before compute.
// New per-tap order:
//   G-read (LDS) -> mid barrier (cheap: no vmem outstanding)
//   -> gstage(ii+1) fused (only ITS L2-hit loads outstanding at its ds_write)
//   -> xstage_load(ii+1) issue (HBM latency starts)
//   -> compute (~1400 cyc, hides the x latency)
//   -> xstage_write (waits loads that already arrived) -> end barrier (cheap).
// No new live registers across compute (g consumed immediately) -> keeps the
// ~68-VGPR no-spill profile.

constexpr int RAD = 2;
constexpr int BB = 2, CC = 16, DD = 48, HH = 128, WW = 256;
constexpr int GG = 75;
constexpr int PLANE = HH * WW;

constexpr int WPT = 4;            // outputs per lane along W
constexpr int DPG = 4;            // depths per wave
constexpr int NWV = 4;            // waves per block
constexpr int DCHUNK = 16;        // depths per block
constexpr int NCH = DD / DCHUNK;  // 3
constexpr int SROWS = DCHUNK + 2; // 18 slab rows (d-1 .. d+16)
constexpr int ROWB = 528;         // f16 x-slab row bytes: [4][512][12]
constexpr int GPL = 1024;         // g pair-plane bytes (256 x uint)

using uint = unsigned int;
typedef __attribute__((ext_vector_type(2))) _Float16 half2v;

__device__ __forceinline__ uint pkrtz(float a, float b) {
  return __builtin_bit_cast(uint, __builtin_amdgcn_cvt_pkrtz(a, b));
}
__device__ __forceinline__ float fdot2(uint a, uint b, float c) {
#if __has_builtin(__builtin_amdgcn_fdot2)
  return __builtin_amdgcn_fdot2(__builtin_bit_cast(half2v, a),
                                __builtin_bit_cast(half2v, b), c, false);
#else
  half2v av = __builtin_bit_cast(half2v, a), bv = __builtin_bit_cast(half2v, b);
  return c + (float)av.x * (float)bv.x + (float)av.y * (float)bv.y;
#endif
}
__device__ __forceinline__ uint alignp(uint a, uint b) {  // {lo:b.hi, hi:a.lo}
  return __builtin_amdgcn_alignbit(a, b, 16);
}
__device__ __forceinline__ unsigned short f2h(float v) {
  return __builtin_bit_cast(unsigned short, (_Float16)v);
}
__device__ __forceinline__ uint getq(const uint4& v, int q) {
  return q == 0 ? v.x : q == 1 ? v.y : q == 2 ? v.z : v.w;
}

template <typename IT, typename OT>   // IT: float (pass1) | ushort f16 (pass2)
__global__ __launch_bounds__(256) void lga_pass(const IT* __restrict__ x,
                                                const float* __restrict__ g,
                                                OT* __restrict__ out) {
  constexpr bool XF32 = (sizeof(IT) == 4);
  __shared__ __align__(16) unsigned char xs[2][SROWS * ROWB];  // 19008 B
  __shared__ __align__(16) unsigned char gsl[9 * GPL];         // 9216 B

  // XCD-bijective swizzle; dch fastest, then h, c, b.
  constexpr int NWG = BB * CC * NCH * HH;   // 12288
  const int bx = blockIdx.x;
  const int lid = (bx & 7) * (NWG >> 3) + (bx >> 3);
  const int dch = lid % NCH;
  const int h   = (lid / NCH) % HH;
  const int c   = (lid / (NCH * HH)) % CC;
  const int b   =  lid / (NCH * HH * CC);

  const int tid = threadIdx.x;
  const int lane = tid & 63;
  const int dg = tid >> 6;                  // wave index (uniform)
  const int w0 = lane * WPT;
  const int d0 = dch * DCHUNK + dg * DPG;

  const IT* xb = x + (size_t)(b * CC + c) * DD * PLANE;
  const float* gb = g + (size_t)b * GG * PLANE;

  // ---- zero init: per-row pads (both bufs) + out-of-range border depth rows
  if (tid < 2 * SROWS) {
    const int buf = tid / SROWS, s = tid % SROWS;
    unsigned char* r = &xs[buf][s * ROWB];
    *reinterpret_cast<uint*>(r) = 0;                           // w = -2,-1
    *reinterpret_cast<uint*>(r + 516) = 0;                     // w = 256,257
    *reinterpret_cast<uint2*>(r + 520) = make_uint2(0, 0);     // w = 258..261
  }
  constexpr int RDW = ROWB / 4;
  if (dch == 0)
    for (int idx = tid; idx < 2 * RDW; idx += 256)
      reinterpret_cast<uint*>(&xs[idx / RDW][0])[idx % RDW] = 0;
  if (dch == NCH - 1)
    for (int idx = tid; idx < 2 * RDW; idx += 256)
      reinterpret_cast<uint*>(&xs[idx / RDW][(SROWS - 1) * ROWB])[idx % RDW] = 0;

  float acc[DPG][WPT];
#pragma unroll
  for (int a = 0; a < DPG; ++a)
#pragma unroll
    for (int q = 0; q < WPT; ++q) acc[a][q] = 0.f;

  const int ilo = (h >= RAD) ? 0 : RAD - h;
  const int him = HH - 1 + RAD - h;
  const int ihi = (him < 4) ? him : 4;

  uint4 srl[5];   // x stage regs (pass1: 4 floats; pass2: .x/.y = 4 halves)

  auto xstage_load = [&](int i) {
    const int hr = h + i - RAD;
#pragma unroll
    for (int t = 0; t < 5; ++t) {
      const int s = dg + NWV * t;
      if (s < SROWS &&
          !(s == 0 && dch == 0) && !(s == SROWS - 1 && dch == NCH - 1)) {
        const int dd = dch * DCHUNK + s - 1;
        if constexpr (XF32) {
          srl[t] = *reinterpret_cast<const uint4*>(xb + (size_t)dd * PLANE + hr * WW + w0);
        } else {
          const uint2 u = *reinterpret_cast<const uint2*>(xb + (size_t)dd * PLANE + hr * WW + w0);
          srl[t].x = u.x; srl[t].y = u.y;
        }
      }
    }
  };
  auto xstage_write = [&](int buf) {
#pragma unroll
    for (int t = 0; t < 5; ++t) {
      const int s = dg + NWV * t;
      if (s < SROWS &&
          !(s == 0 && dch == 0) && !(s == SROWS - 1 && dch == NCH - 1)) {
        uint lo, hi;
        if constexpr (XF32) {
          lo = pkrtz(__uint_as_float(srl[t].x), __uint_as_float(srl[t].y));
          hi = pkrtz(__uint_as_float(srl[t].z), __uint_as_float(srl[t].w));
        } else {
          lo = srl[t].x; hi = srl[t].y;
        }
        unsigned char* rp = &xs[buf][s * ROWB + 4 + 8 * lane];  // core @ w0
        *reinterpret_cast<uint*>(rp) = lo;
        *reinterpret_cast<uint*>(rp + 4) = hi;
      }
    }
  };

  // g stage: pack f16 j-pairs into 9 LDS planes (p = k*3+jp), once/block-tap.
  // Fused load->write: called while NO other vmem is outstanding, so its
  // ds_write waits only the g loads (L2-hit, ~200-300 cyc).
  auto gstage = [&](int i) {
#pragma unroll
    for (int r = 0; r < 3; ++r) {
      const int item = tid + (r << 8);
      if (item < 576) {                       // 9 planes x 64 slots
        const int p = item >> 6, slot = item & 63;
        const int k = p / 3, jp = p % 3;
        const int chA = (i * 5 + 2 * jp) * 3 + k;
        const float4 a = *reinterpret_cast<const float4*>(
            gb + (size_t)chA * PLANE + h * WW + 4 * slot);
        float4 bq = make_float4(0.f, 0.f, 0.f, 0.f);
        if (jp < 2)
          bq = *reinterpret_cast<const float4*>(
              gb + (size_t)(chA + 3) * PLANE + h * WW + 4 * slot);
        uint4 u;
        u.x = pkrtz(a.x, bq.x); u.y = pkrtz(a.y, bq.y);
        u.z = pkrtz(a.z, bq.z); u.w = pkrtz(a.w, bq.w);
        *reinterpret_cast<uint4*>(&gsl[p * GPL + 16 * slot]) = u;
      }
    }
  };

  int cur = 0;
  gstage(ilo);
  xstage_load(ilo);
  xstage_write(0);
  __syncthreads();

  for (int ii = ilo; ii <= ihi; ++ii) {
    // G pairs for this tap: plane p, pixels w0..w0+3 (16B/lane). LDS-only.
    uint4 G[9];
#pragma unroll
    for (int p = 0; p < 9; ++p)
      G[p] = *reinterpret_cast<const uint4*>(&gsl[p * GPL + 16 * lane]);

    // Mid barrier BEFORE any vmem is issued this tap: drains only lgkm
    // (G reads) -> cheap. Protects gsl for the overwrite below.
    __syncthreads();

    if (ii < ihi) {
      gstage(ii + 1);         // g loads+writes first (only vmem outstanding)
      xstage_load(ii + 1);    // then issue HBM x loads; consumed after compute
    }

    const unsigned char* wb = &xs[cur][(dg * DPG) * ROWB] + 8 * lane;
#pragma unroll
    for (int a = -1; a <= DPG; ++a) {       // slab rows d0-1 .. d0+4
      const unsigned char* rp = wb + (a + 1) * ROWB;
      // even pairs E[m] = {v2m, v2m+1}; window v0..v9 (v8,v9 pad-safe)
      const uint2 e01 = *reinterpret_cast<const uint2*>(rp);
      const uint2 e23 = *reinterpret_cast<const uint2*>(rp + 8);
      const uint  e4  = *reinterpret_cast<const uint*>(rp + 16);
      uint P[9];
      P[0] = e01.x; P[2] = e01.y; P[4] = e23.x; P[6] = e23.y; P[8] = e4;
      P[1] = alignp(P[2], P[0]);
      P[3] = alignp(P[4], P[2]);
      P[5] = alignp(P[6], P[4]);
      P[7] = alignp(P[8], P[6]);
      // scatter: x row d0+a feeds acc[a+1-k]; per (k,ai,q): 3 dot2
#pragma unroll
      for (int k = 0; k < 3; ++k) {
        const int ai = a + 1 - k;
        if (ai < 0 || ai >= DPG) continue;  // compile-time
#pragma unroll
        for (int q = 0; q < WPT; ++q) {
          float t = acc[ai][q];
          t = fdot2(getq(G[k * 3 + 0], q), P[q], t);
          t = fdot2(getq(G[k * 3 + 1], q), P[q + 2], t);
          t = fdot2(getq(G[k * 3 + 2], q), P[q + 4], t);
          acc[ai][q] = t;
        }
      }
    }
    if (ii < ihi) xstage_write(cur ^ 1);    // x loads arrived during compute
    __syncthreads();                        // cheap: ds writes only
    cur ^= 1;
  }

  const int obase = d0 * PLANE + h * WW + w0;
  if constexpr (sizeof(OT) == 4) {
    float* ob = (float*)out + (size_t)(b * CC + c) * DD * PLANE;
#pragma unroll
    for (int ai = 0; ai < DPG; ++ai) {
      float4 t; t.x = acc[ai][0]; t.y = acc[ai][1]; t.z = acc[ai][2]; t.w = acc[ai][3];
      *reinterpret_cast<float4*>(ob + obase + ai * PLANE) = t;
    }
  } else {
    unsigned short* ob = (unsigned short*)out + (size_t)(b * CC + c) * DD * PLANE;
#pragma unroll
    for (int ai = 0; ai < DPG; ++ai) {
      ushort4 t; t.x = f2h(acc[ai][0]); t.y = f2h(acc[ai][1]);
      t.z = f2h(acc[ai][2]); t.w = f2h(acc[ai][3]);
      *reinterpret_cast<ushort4*>(ob + obase + ai * PLANE) = t;
    }
  }
}

extern "C" void kernel_launch(void* const* d_in, const int* in_sizes, int n_in,
                              void* d_out, int out_size, void* d_ws, size_t ws_size,
                              hipStream_t stream) {
  const float* x = (const float*)d_in[0];
  const float* g = (const float*)d_in[1];
  float* out = (float*)d_out;
  unsigned short* y = (unsigned short*)d_ws;   // f16 intermediate (100 MB)

  const dim3 grid(BB * CC * NCH * HH);   // 12288
  const dim3 block(64 * NWV);            // 256

  lga_pass<float, unsigned short><<<grid, block, 0, stream>>>(x, g, y);
  lga_pass<unsigned short, float><<<grid, block, 0, stream>>>(y, g, out);
}

// Round 14
// 409.420 us; speedup vs baseline: 1.0359x; 1.0359x over previous
//
#include <hip/hip_runtime.h>
#include <hip/hip_bf16.h>

// LGA3D2: out = A_g(A_g(x)); A_g is a 5x5 spatial x 3-depth guided aggregation.
// out[b,c,d,h,w] = sum_{i,j in 5x5, k in 0..2} g[b,(i*5+j)*3+k,h,w] * x[b,c,d+k-1,h+i-2,w+j-2]
// x: [B,C,D,H,W] fp32, g: [B,75,H,W] fp32.
//
// R14: three kernels.
//  0) cvt: x (fp32) -> xh (f16) streaming; xh lives in d_out's storage.
//  1) lga_pass<ushort>: xh -> y (f16, in d_ws).
//  2) lga_pass<float>:  y -> out (fp32, overwrites d_out; reads only d_ws).
// Rationale (R12/R13 dispatch data): f16-input pass runs ~140us vs fp32-input
// ~275us (2x stage bytes + cold-HBM latency). Converting once makes both
// passes read L3-resident 100MB f16 buffers.
// Plus: cheap barriers (lgkmcnt(0) + builtin s_barrier, m201 pattern) so the
// x stage loads issued before the mid-barrier stay in flight through
// gstage+compute (__syncthreads would drain vmcnt(0) at every barrier).

constexpr int RAD = 2;
constexpr int BB = 2, CC = 16, DD = 48, HH = 128, WW = 256;
constexpr int GG = 75;
constexpr int PLANE = HH * WW;

constexpr int WPT = 4;            // outputs per lane along W
constexpr int DPG = 4;            // depths per wave
constexpr int NWV = 4;            // waves per block
constexpr int DCHUNK = 16;        // depths per block
constexpr int NCH = DD / DCHUNK;  // 3
constexpr int SROWS = DCHUNK + 2; // 18 slab rows (d-1 .. d+16)
constexpr int ROWB = 528;         // f16 x-slab row bytes: [4][512][12]
constexpr int GPL = 1024;         // g pair-plane bytes (256 x uint)

using uint = unsigned int;
typedef __attribute__((ext_vector_type(2))) _Float16 half2v;

__device__ __forceinline__ uint pkrtz(float a, float b) {
  return __builtin_bit_cast(uint, __builtin_amdgcn_cvt_pkrtz(a, b));
}
__device__ __forceinline__ float fdot2(uint a, uint b, float c) {
#if __has_builtin(__builtin_amdgcn_fdot2)
  return __builtin_amdgcn_fdot2(__builtin_bit_cast(half2v, a),
                                __builtin_bit_cast(half2v, b), c, false);
#else
  half2v av = __builtin_bit_cast(half2v, a), bv = __builtin_bit_cast(half2v, b);
  return c + (float)av.x * (float)bv.x + (float)av.y * (float)bv.y;
#endif
}
__device__ __forceinline__ uint alignp(uint a, uint b) {  // {lo:b.hi, hi:a.lo}
  return __builtin_amdgcn_alignbit(a, b, 16);
}
__device__ __forceinline__ unsigned short f2h(float v) {
  return __builtin_bit_cast(unsigned short, (_Float16)v);
}
__device__ __forceinline__ uint getq(const uint4& v, int q) {
  return q == 0 ? v.x : q == 1 ? v.y : q == 2 ? v.z : v.w;
}
// Workgroup barrier WITHOUT the vmcnt(0) drain __syncthreads emits:
// LDS ordering (lgkmcnt) is enforced; global loads in VGPRs stay in flight.
__device__ __forceinline__ void wg_barrier() {
  asm volatile("s_waitcnt lgkmcnt(0)" ::: "memory");
  __builtin_amdgcn_s_barrier();
}

// ---- kernel 0: fp32 -> f16 streaming convert
__global__ __launch_bounds__(256) void cvt_f32_f16(const float* __restrict__ x,
                                                   unsigned short* __restrict__ xh,
                                                   int n4) {
  const int stride = gridDim.x * blockDim.x;
  for (int i = blockIdx.x * blockDim.x + threadIdx.x; i < n4; i += stride) {
    const float4 v = *reinterpret_cast<const float4*>(x + (size_t)i * 4);
    uint2 u; u.x = pkrtz(v.x, v.y); u.y = pkrtz(v.z, v.w);
    *reinterpret_cast<uint2*>(xh + (size_t)i * 4) = u;
  }
}

// ---- the aggregation pass: f16 input, OT output (f16 or f32)
template <typename OT>
__global__ __launch_bounds__(256) void lga_pass(const unsigned short* __restrict__ x,
                                                const float* __restrict__ g,
                                                OT* __restrict__ out) {
  __shared__ __align__(16) unsigned char xs[2][SROWS * ROWB];  // 19008 B
  __shared__ __align__(16) unsigned char gsl[9 * GPL];         // 9216 B

  // XCD-bijective swizzle; dch fastest, then h, c, b.
  constexpr int NWG = BB * CC * NCH * HH;   // 12288
  const int bx = blockIdx.x;
  const int lid = (bx & 7) * (NWG >> 3) + (bx >> 3);
  const int dch = lid % NCH;
  const int h   = (lid / NCH) % HH;
  const int c   = (lid / (NCH * HH)) % CC;
  const int b   =  lid / (NCH * HH * CC);

  const int tid = threadIdx.x;
  const int lane = tid & 63;
  const int dg = tid >> 6;                  // wave index (uniform)
  const int w0 = lane * WPT;
  const int d0 = dch * DCHUNK + dg * DPG;

  const unsigned short* xb = x + (size_t)(b * CC + c) * DD * PLANE;
  const float* gb = g + (size_t)b * GG * PLANE;

  // ---- zero init: per-row pads (both bufs) + out-of-range border depth rows
  if (tid < 2 * SROWS) {
    const int buf = tid / SROWS, s = tid % SROWS;
    unsigned char* r = &xs[buf][s * ROWB];
    *reinterpret_cast<uint*>(r) = 0;                           // w = -2,-1
    *reinterpret_cast<uint*>(r + 516) = 0;                     // w = 256,257
    *reinterpret_cast<uint2*>(r + 520) = make_uint2(0, 0);     // w = 258..261
  }
  constexpr int RDW = ROWB / 4;
  if (dch == 0)
    for (int idx = tid; idx < 2 * RDW; idx += 256)
      reinterpret_cast<uint*>(&xs[idx / RDW][0])[idx % RDW] = 0;
  if (dch == NCH - 1)
    for (int idx = tid; idx < 2 * RDW; idx += 256)
      reinterpret_cast<uint*>(&xs[idx / RDW][(SROWS - 1) * ROWB])[idx % RDW] = 0;

  float acc[DPG][WPT];
#pragma unroll
  for (int a = 0; a < DPG; ++a)
#pragma unroll
    for (int q = 0; q < WPT; ++q) acc[a][q] = 0.f;

  const int ilo = (h >= RAD) ? 0 : RAD - h;
  const int him = HH - 1 + RAD - h;
  const int ihi = (him < 4) ? him : 4;

  uint2 srl[5];   // x stage regs: 4 halves per row

  auto xstage_load = [&](int i) {
    const int hr = h + i - RAD;
#pragma unroll
    for (int t = 0; t < 5; ++t) {
      const int s = dg + NWV * t;
      if (s < SROWS &&
          !(s == 0 && dch == 0) && !(s == SROWS - 1 && dch == NCH - 1)) {
        const int dd = dch * DCHUNK + s - 1;
        srl[t] = *reinterpret_cast<const uint2*>(xb + (size_t)dd * PLANE + hr * WW + w0);
      }
    }
  };
  auto xstage_write = [&](int buf) {
#pragma unroll
    for (int t = 0; t < 5; ++t) {
      const int s = dg + NWV * t;
      if (s < SROWS &&
          !(s == 0 && dch == 0) && !(s == SROWS - 1 && dch == NCH - 1)) {
        unsigned char* rp = &xs[buf][s * ROWB + 4 + 8 * lane];  // core @ w0
        *reinterpret_cast<uint*>(rp) = srl[t].x;
        *reinterpret_cast<uint*>(rp + 4) = srl[t].y;
      }
    }
  };

  // g stage: pack f16 j-pairs into 9 LDS planes (p = k*3+jp), once/block-tap.
  auto gstage = [&](int i) {
#pragma unroll
    for (int r = 0; r < 3; ++r) {
      const int item = tid + (r << 8);
      if (item < 576) {                       // 9 planes x 64 slots
        const int p = item >> 6, slot = item & 63;
        const int k = p / 3, jp = p % 3;
        const int chA = (i * 5 + 2 * jp) * 3 + k;
        const float4 a = *reinterpret_cast<const float4*>(
            gb + (size_t)chA * PLANE + h * WW + 4 * slot);
        float4 bq = make_float4(0.f, 0.f, 0.f, 0.f);
        if (jp < 2)
          bq = *reinterpret_cast<const float4*>(
              gb + (size_t)(chA + 3) * PLANE + h * WW + 4 * slot);
        uint4 u;
        u.x = pkrtz(a.x, bq.x); u.y = pkrtz(a.y, bq.y);
        u.z = pkrtz(a.z, bq.z); u.w = pkrtz(a.w, bq.w);
        *reinterpret_cast<uint4*>(&gsl[p * GPL + 16 * slot]) = u;
      }
    }
  };

  int cur = 0;
  gstage(ilo);
  xstage_load(ilo);
  xstage_write(0);
  wg_barrier();

  for (int ii = ilo; ii <= ihi; ++ii) {
    // G pairs for this tap: plane p, pixels w0..w0+3 (16B/lane). LDS-only.
    uint4 G[9];
#pragma unroll
    for (int p = 0; p < 9; ++p)
      G[p] = *reinterpret_cast<const uint4*>(&gsl[p * GPL + 16 * lane]);

    if (ii < ihi) xstage_load(ii + 1);   // issue HBM/L3 loads; NOT drained by
    wg_barrier();                        // the cheap barrier (lgkm only)
    if (ii < ihi) gstage(ii + 1);        // g loads newer than x; counted vmcnt

    const unsigned char* wb = &xs[cur][(dg * DPG) * ROWB] + 8 * lane;
#pragma unroll
    for (int a = -1; a <= DPG; ++a) {       // slab rows d0-1 .. d0+4
      const unsigned char* rp = wb + (a + 1) * ROWB;
      const uint2 e01 = *reinterpret_cast<const uint2*>(rp);
      const uint2 e23 = *reinterpret_cast<const uint2*>(rp + 8);
      const uint  e4  = *reinterpret_cast<const uint*>(rp + 16);
      uint P[9];
      P[0] = e01.x; P[2] = e01.y; P[4] = e23.x; P[6] = e23.y; P[8] = e4;
      P[1] = alignp(P[2], P[0]);
      P[3] = alignp(P[4], P[2]);
      P[5] = alignp(P[6], P[4]);
      P[7] = alignp(P[8], P[6]);
#pragma unroll
      for (int k = 0; k < 3; ++k) {
        const int ai = a + 1 - k;
        if (ai < 0 || ai >= DPG) continue;  // compile-time
#pragma unroll
        for (int q = 0; q < WPT; ++q) {
          float t = acc[ai][q];
          t = fdot2(getq(G[k * 3 + 0], q), P[q], t);
          t = fdot2(getq(G[k * 3 + 1], q), P[q + 2], t);
          t = fdot2(getq(G[k * 3 + 2], q), P[q + 4], t);
          acc[ai][q] = t;
        }
      }
    }
    if (ii < ihi) xstage_write(cur ^ 1);    // x loads arrived during compute
    wg_barrier();
    cur ^= 1;
  }

  const int obase = d0 * PLANE + h * WW + w0;
  if constexpr (sizeof(OT) == 4) {
    float* ob = (float*)out + (size_t)(b * CC + c) * DD * PLANE;
#pragma unroll
    for (int ai = 0; ai < DPG; ++ai) {
      float4 t; t.x = acc[ai][0]; t.y = acc[ai][1]; t.z = acc[ai][2]; t.w = acc[ai][3];
      *reinterpret_cast<float4*>(ob + obase + ai * PLANE) = t;
    }
  } else {
    unsigned short* ob = (unsigned short*)out + (size_t)(b * CC + c) * DD * PLANE;
#pragma unroll
    for (int ai = 0; ai < DPG; ++ai) {
      ushort4 t; t.x = f2h(acc[ai][0]); t.y = f2h(acc[ai][1]);
      t.z = f2h(acc[ai][2]); t.w = f2h(acc[ai][3]);
      *reinterpret_cast<ushort4*>(ob + obase + ai * PLANE) = t;
    }
  }
}

extern "C" void kernel_launch(void* const* d_in, const int* in_sizes, int n_in,
                              void* d_out, int out_size, void* d_ws, size_t ws_size,
                              hipStream_t stream) {
  const float* x = (const float*)d_in[0];
  const float* g = (const float*)d_in[1];
  float* out = (float*)d_out;

  const size_t elems = (size_t)BB * CC * DD * HH * WW;   // 50,331,648
  // xh (f16) borrows d_out's storage (100MB of 201MB); y (f16) in d_ws.
  // Pass2 reads ONLY y (d_ws) and overwrites d_out with the final fp32 -> no
  // read-after-write hazard on d_out.
  unsigned short* xh = (unsigned short*)d_out;
  unsigned short* y  = (unsigned short*)d_ws;

  cvt_f32_f16<<<2048, 256, 0, stream>>>(x, xh, (int)(elems / 4));

  const dim3 grid(BB * CC * NCH * HH);   // 12288
  const dim3 block(64 * NWV);            // 256
  lga_pass<unsigned short><<<grid, block, 0, stream>>>(xh, g, y);
  lga_pass<float><<<grid, block, 0, stream>>>(y, g, out);
}

// Round 15
// 377.639 us; speedup vs baseline: 1.1231x; 1.0842x over previous
//
#include <hip/hip_runtime.h>
#include <hip/hip_bf16.h>

// LGA3D2: out = A_g(A_g(x)); A_g is a 5x5 spatial x 3-depth guided aggregation.
// out[b,c,d,h,w] = sum_{i,j in 5x5, k in 0..2} g[b,(i*5+j)*3+k,h,w] * x[b,c,d+k-1,h+i-2,w+j-2]
// x: [B,C,D,H,W] fp32, g: [B,75,H,W] fp32.
//
// R15: best-of-breed recombination.
//  - cvt: x fp32 -> xh f16 (xh borrows d_out's first 100.6MB) so BOTH passes
//    read L3-warm f16 (R14's proven pass1 fix).
//  - lga_pass: R12's EXACT loop order with __syncthreads (R14's wg_barrier
//    regressed pass2 140->201us; the compiler schedules its own barriers
//    better than hand-rolled lgkm-only asm - rule #18 territory).
//  - gpack (new): packed f16 j-pair G planes precomputed ONCE into global
//    (11.8MB at d_ws tail, gated on ws_size; fallback = in-kernel packing).
//    gstage becomes a pure uint4 L2-load -> ds_write copy: removes 4 pkrtz +
//    a 2nd float4 load + addressing per item from every block-tap.

constexpr int RAD = 2;
constexpr int BB = 2, CC = 16, DD = 48, HH = 128, WW = 256;
constexpr int GG = 75;
constexpr int PLANE = HH * WW;

constexpr int WPT = 4;            // outputs per lane along W
constexpr int DPG = 4;            // depths per wave
constexpr int NWV = 4;            // waves per block
constexpr int DCHUNK = 16;        // depths per block
constexpr int NCH = DD / DCHUNK;  // 3
constexpr int SROWS = DCHUNK + 2; // 18 slab rows (d-1 .. d+16)
constexpr int ROWB = 528;         // f16 x-slab row bytes: [4][512][12]
constexpr int GPL = 1024;         // g pair-plane bytes (256 x uint)
constexpr size_t GPB_UINTS = (size_t)BB * 5 * 9 * PLANE;   // packed G uints

using uint = unsigned int;
typedef __attribute__((ext_vector_type(2))) _Float16 half2v;

__device__ __forceinline__ uint pkrtz(float a, float b) {
  return __builtin_bit_cast(uint, __builtin_amdgcn_cvt_pkrtz(a, b));
}
__device__ __forceinline__ float fdot2(uint a, uint b, float c) {
#if __has_builtin(__builtin_amdgcn_fdot2)
  return __builtin_amdgcn_fdot2(__builtin_bit_cast(half2v, a),
                                __builtin_bit_cast(half2v, b), c, false);
#else
  half2v av = __builtin_bit_cast(half2v, a), bv = __builtin_bit_cast(half2v, b);
  return c + (float)av.x * (float)bv.x + (float)av.y * (float)bv.y;
#endif
}
__device__ __forceinline__ uint alignp(uint a, uint b) {  // {lo:b.hi, hi:a.lo}
  return __builtin_amdgcn_alignbit(a, b, 16);
}
__device__ __forceinline__ unsigned short f2h(float v) {
  return __builtin_bit_cast(unsigned short, (_Float16)v);
}
__device__ __forceinline__ uint getq(const uint4& v, int q) {
  return q == 0 ? v.x : q == 1 ? v.y : q == 2 ? v.z : v.w;
}

// ---- kernel 0: fp32 -> f16 streaming convert
__global__ __launch_bounds__(256) void cvt_f32_f16(const float* __restrict__ x,
                                                   unsigned short* __restrict__ xh,
                                                   int n4) {
  const int stride = gridDim.x * blockDim.x;
  for (int i = blockIdx.x * blockDim.x + threadIdx.x; i < n4; i += stride) {
    const float4 v = *reinterpret_cast<const float4*>(x + (size_t)i * 4);
    uint2 u; u.x = pkrtz(v.x, v.y); u.y = pkrtz(v.z, v.w);
    *reinterpret_cast<uint2*>(xh + (size_t)i * 4) = u;
  }
}

// ---- kernel 0b: pack g into f16 j-pair planes.
// gbuf uint index: ((b*5+i)*9 + p)*PLANE + h*WW + w, p = k*3+jp.
// value = {f16 g[(i*5+2jp)*3+k](h,w), f16 g[(i*5+2jp+1)*3+k](h,w) or 0}.
__global__ __launch_bounds__(256) void gpack(const float* __restrict__ g,
                                             uint* __restrict__ gbuf) {
  const int n4 = (int)(GPB_UINTS / 4);    // uint4 items
  const int stride = gridDim.x * blockDim.x;
  for (int it = blockIdx.x * blockDim.x + threadIdx.x; it < n4; it += stride) {
    const int w4 = (it % (PLANE / 4)) * 4;          // w of first uint
    const int rest = it / (PLANE / 4);              // (b*5+i)*9 + p
    const int p = rest % 9;
    const int bi = rest / 9;                        // b*5 + i
    const int i = bi % 5, b = bi / 5;
    const int k = p / 3, jp = p % 3;
    const int chA = (i * 5 + 2 * jp) * 3 + k;
    const float* gb = g + (size_t)b * GG * PLANE;
    const float4 a = *reinterpret_cast<const float4*>(gb + (size_t)chA * PLANE + w4);
    float4 bq = make_float4(0.f, 0.f, 0.f, 0.f);
    if (jp < 2)
      bq = *reinterpret_cast<const float4*>(gb + (size_t)(chA + 3) * PLANE + w4);
    uint4 u;
    u.x = pkrtz(a.x, bq.x); u.y = pkrtz(a.y, bq.y);
    u.z = pkrtz(a.z, bq.z); u.w = pkrtz(a.w, bq.w);
    *reinterpret_cast<uint4*>(gbuf + (size_t)it * 4) = u;
  }
}

// ---- the aggregation pass: f16 input, OT output (f16 or f32)
template <typename OT, bool PACKED>
__global__ __launch_bounds__(256) void lga_pass(const unsigned short* __restrict__ x,
                                                const float* __restrict__ g,
                                                const uint* __restrict__ gpk,
                                                OT* __restrict__ out) {
  __shared__ __align__(16) unsigned char xs[2][SROWS * ROWB];  // 19008 B
  __shared__ __align__(16) unsigned char gsl[9 * GPL];         // 9216 B

  // XCD-bijective swizzle; dch fastest, then h, c, b.
  constexpr int NWG = BB * CC * NCH * HH;   // 12288
  const int bx = blockIdx.x;
  const int lid = (bx & 7) * (NWG >> 3) + (bx >> 3);
  const int dch = lid % NCH;
  const int h   = (lid / NCH) % HH;
  const int c   = (lid / (NCH * HH)) % CC;
  const int b   =  lid / (NCH * HH * CC);

  const int tid = threadIdx.x;
  const int lane = tid & 63;
  const int dg = tid >> 6;                  // wave index (uniform)
  const int w0 = lane * WPT;
  const int d0 = dch * DCHUNK + dg * DPG;

  const unsigned short* xb = x + (size_t)(b * CC + c) * DD * PLANE;
  const float* gb = g + (size_t)b * GG * PLANE;

  // ---- zero init: per-row pads (both bufs) + out-of-range border depth rows
  if (tid < 2 * SROWS) {
    const int buf = tid / SROWS, s = tid % SROWS;
    unsigned char* r = &xs[buf][s * ROWB];
    *reinterpret_cast<uint*>(r) = 0;                           // w = -2,-1
    *reinterpret_cast<uint*>(r + 516) = 0;                     // w = 256,257
    *reinterpret_cast<uint2*>(r + 520) = make_uint2(0, 0);     // w = 258..261
  }
  constexpr int RDW = ROWB / 4;
  if (dch == 0)
    for (int idx = tid; idx < 2 * RDW; idx += 256)
      reinterpret_cast<uint*>(&xs[idx / RDW][0])[idx % RDW] = 0;
  if (dch == NCH - 1)
    for (int idx = tid; idx < 2 * RDW; idx += 256)
      reinterpret_cast<uint*>(&xs[idx / RDW][(SROWS - 1) * ROWB])[idx % RDW] = 0;

  float acc[DPG][WPT];
#pragma unroll
  for (int a = 0; a < DPG; ++a)
#pragma unroll
    for (int q = 0; q < WPT; ++q) acc[a][q] = 0.f;

  const int ilo = (h >= RAD) ? 0 : RAD - h;
  const int him = HH - 1 + RAD - h;
  const int ihi = (him < 4) ? him : 4;

  uint2 srl[5];   // x stage regs: 4 halves per row

  auto xstage_load = [&](int i) {
    const int hr = h + i - RAD;
#pragma unroll
    for (int t = 0; t < 5; ++t) {
      const int s = dg + NWV * t;
      if (s < SROWS &&
          !(s == 0 && dch == 0) && !(s == SROWS - 1 && dch == NCH - 1)) {
        const int dd = dch * DCHUNK + s - 1;
        srl[t] = *reinterpret_cast<const uint2*>(xb + (size_t)dd * PLANE + hr * WW + w0);
      }
    }
  };
  auto xstage_write = [&](int buf) {
#pragma unroll
    for (int t = 0; t < 5; ++t) {
      const int s = dg + NWV * t;
      if (s < SROWS &&
          !(s == 0 && dch == 0) && !(s == SROWS - 1 && dch == NCH - 1)) {
        unsigned char* rp = &xs[buf][s * ROWB + 4 + 8 * lane];  // core @ w0
        *reinterpret_cast<uint*>(rp) = srl[t].x;
        *reinterpret_cast<uint*>(rp + 4) = srl[t].y;
      }
    }
  };

  // g stage: 9 f16 j-pair planes into LDS, once per block-tap.
  auto gstage = [&](int i) {
#pragma unroll
    for (int r = 0; r < 3; ++r) {
      const int item = tid + (r << 8);
      if (item < 576) {                       // 9 planes x 64 slots
        const int p = item >> 6, slot = item & 63;
        uint4 u;
        if constexpr (PACKED) {
          // pure copy from the precomputed buffer (L2/L3-resident)
          u = *reinterpret_cast<const uint4*>(
              gpk + ((size_t)((b * 5 + i) * 9 + p)) * PLANE + h * WW + 4 * slot);
        } else {
          const int k = p / 3, jp = p % 3;
          const int chA = (i * 5 + 2 * jp) * 3 + k;
          const float4 a = *reinterpret_cast<const float4*>(
              gb + (size_t)chA * PLANE + h * WW + 4 * slot);
          float4 bq = make_float4(0.f, 0.f, 0.f, 0.f);
          if (jp < 2)
            bq = *reinterpret_cast<const float4*>(
                gb + (size_t)(chA + 3) * PLANE + h * WW + 4 * slot);
          u.x = pkrtz(a.x, bq.x); u.y = pkrtz(a.y, bq.y);
          u.z = pkrtz(a.z, bq.z); u.w = pkrtz(a.w, bq.w);
        }
        *reinterpret_cast<uint4*>(&gsl[p * GPL + 16 * slot]) = u;
      }
    }
  };

  int cur = 0;
  gstage(ilo);
  xstage_load(ilo);
  xstage_write(0);
  __syncthreads();

  for (int ii = ilo; ii <= ihi; ++ii) {
    // G pairs for this tap: plane p, pixels w0..w0+3 (16B/lane). LDS-only.
    uint4 G[9];
#pragma unroll
    for (int p = 0; p < 9; ++p)
      G[p] = *reinterpret_cast<const uint4*>(&gsl[p * GPL + 16 * lane]);

    if (ii < ihi) xstage_load(ii + 1);
    __syncthreads();                        // G consumed -> gsl writable
    if (ii < ihi) gstage(ii + 1);           // lands under compute

    const unsigned char* wb = &xs[cur][(dg * DPG) * ROWB] + 8 * lane;
#pragma unroll
    for (int a = -1; a <= DPG; ++a) {       // slab rows d0-1 .. d0+4
      const unsigned char* rp = wb + (a + 1) * ROWB;
      const uint2 e01 = *reinterpret_cast<const uint2*>(rp);
      const uint2 e23 = *reinterpret_cast<const uint2*>(rp + 8);
      const uint  e4  = *reinterpret_cast<const uint*>(rp + 16);
      uint P[9];
      P[0] = e01.x; P[2] = e01.y; P[4] = e23.x; P[6] = e23.y; P[8] = e4;
      P[1] = alignp(P[2], P[0]);
      P[3] = alignp(P[4], P[2]);
      P[5] = alignp(P[6], P[4]);
      P[7] = alignp(P[8], P[6]);
#pragma unroll
      for (int k = 0; k < 3; ++k) {
        const int ai = a + 1 - k;
        if (ai < 0 || ai >= DPG) continue;  // compile-time
#pragma unroll
        for (int q = 0; q < WPT; ++q) {
          float t = acc[ai][q];
          t = fdot2(getq(G[k * 3 + 0], q), P[q], t);
          t = fdot2(getq(G[k * 3 + 1], q), P[q + 2], t);
          t = fdot2(getq(G[k * 3 + 2], q), P[q + 4], t);
          acc[ai][q] = t;
        }
      }
    }
    if (ii < ihi) xstage_write(cur ^ 1);    // x loads arrived during compute
    __syncthreads();
    cur ^= 1;
  }

  const int obase = d0 * PLANE + h * WW + w0;
  if constexpr (sizeof(OT) == 4) {
    float* ob = (float*)out + (size_t)(b * CC + c) * DD * PLANE;
#pragma unroll
    for (int ai = 0; ai < DPG; ++ai) {
      float4 t; t.x = acc[ai][0]; t.y = acc[ai][1]; t.z = acc[ai][2]; t.w = acc[ai][3];
      *reinterpret_cast<float4*>(ob + obase + ai * PLANE) = t;
    }
  } else {
    unsigned short* ob = (unsigned short*)out + (size_t)(b * CC + c) * DD * PLANE;
#pragma unroll
    for (int ai = 0; ai < DPG; ++ai) {
      ushort4 t; t.x = f2h(acc[ai][0]); t.y = f2h(acc[ai][1]);
      t.z = f2h(acc[ai][2]); t.w = f2h(acc[ai][3]);
      *reinterpret_cast<ushort4*>(ob + obase + ai * PLANE) = t;
    }
  }
}

extern "C" void kernel_launch(void* const* d_in, const int* in_sizes, int n_in,
                              void* d_out, int out_size, void* d_ws, size_t ws_size,
                              hipStream_t stream) {
  const float* x = (const float*)d_in[0];
  const float* g = (const float*)d_in[1];
  float* out = (float*)d_out;

  const size_t elems = (size_t)BB * CC * DD * HH * WW;   // 50,331,648
  // xh (f16) borrows d_out's first 100.6MB; y (f16) at d_ws start.
  // Pass2 reads only d_ws (y + optional gpk) and overwrites d_out.
  unsigned short* xh = (unsigned short*)d_out;
  unsigned short* y  = (unsigned short*)d_ws;

  cvt_f32_f16<<<2048, 256, 0, stream>>>(x, xh, (int)(elems / 4));

  const dim3 grid(BB * CC * NCH * HH);   // 12288
  const dim3 block(64 * NWV);            // 256

  // Packed-G buffer lives after y in d_ws if it fits (y:100.6MB + gpk:11.8MB).
  const size_t need = elems * 2 + GPB_UINTS * 4;
  if (ws_size >= need) {
    uint* gbuf = (uint*)((char*)d_ws + elems * 2);
    gpack<<<1440, 256, 0, stream>>>(g, gbuf);
    lga_pass<unsigned short, true><<<grid, block, 0, stream>>>(xh, g, gbuf, y);
    lga_pass<float, true><<<grid, block, 0, stream>>>(y, g, gbuf, out);
  } else {
    lga_pass<unsigned short, false><<<grid, block, 0, stream>>>(xh, g, nullptr, y);
    lga_pass<float, false><<<grid, block, 0, stream>>>(y, g, nullptr, out);
  }
}

// Round 16
// 369.258 us; speedup vs baseline: 1.1485x; 1.0227x over previous
//
#include <hip/hip_runtime.h>
#include <hip/hip_bf16.h>

// LGA3D2: out = A_g(A_g(x)); A_g is a 5x5 spatial x 3-depth guided aggregation.
// out[b,c,d,h,w] = sum_{i,j in 5x5, k in 0..2} g[b,(i*5+j)*3+k,h,w] * x[b,c,d+k-1,h+i-2,w+j-2]
// x: [B,C,D,H,W] fp32, g: [B,75,H,W] fp32.
//
// R16 = R15 (cvt->f16, gpack'd G planes, f16 LDS slabs + v_dot2_f32_f16,
// __syncthreads barriers) with the per-tap schedule fixed (full T14 split):
//   R15 issued xstage_load BEFORE the mid __syncthreads -> the barrier's
//   mandatory vmcnt(0) drained those loads with nothing overlapping; and
//   gstage was a fused load->ds_write -> its L2 latency was exposed before
//   compute. New tap order:
//     G[9] <- gsl ; MID BARRIER (no vmem outstanding -> free drain)
//     -> issue g-loads (3x uint4 regs) + x-loads (5x uint2 regs)
//     -> compute 6 rows (~800+ cyc, hides both)
//     -> g-write + x-write (loads arrived) ; END BARRIER.
//   Single gsl buffer stays safe: all waves consumed G before the mid
//   barrier, writes land before the end barrier.

constexpr int RAD = 2;
constexpr int BB = 2, CC = 16, DD = 48, HH = 128, WW = 256;
constexpr int GG = 75;
constexpr int PLANE = HH * WW;

constexpr int WPT = 4;            // outputs per lane along W
constexpr int DPG = 4;            // depths per wave
constexpr int NWV = 4;            // waves per block
constexpr int DCHUNK = 16;        // depths per block
constexpr int NCH = DD / DCHUNK;  // 3
constexpr int SROWS = DCHUNK + 2; // 18 slab rows (d-1 .. d+16)
constexpr int ROWB = 528;         // f16 x-slab row bytes: [4][512][12]
constexpr int GPL = 1024;         // g pair-plane bytes (256 x uint)
constexpr size_t GPB_UINTS = (size_t)BB * 5 * 9 * PLANE;   // packed G uints

using uint = unsigned int;
typedef __attribute__((ext_vector_type(2))) _Float16 half2v;

__device__ __forceinline__ uint pkrtz(float a, float b) {
  return __builtin_bit_cast(uint, __builtin_amdgcn_cvt_pkrtz(a, b));
}
__device__ __forceinline__ float fdot2(uint a, uint b, float c) {
#if __has_builtin(__builtin_amdgcn_fdot2)
  return __builtin_amdgcn_fdot2(__builtin_bit_cast(half2v, a),
                                __builtin_bit_cast(half2v, b), c, false);
#else
  half2v av = __builtin_bit_cast(half2v, a), bv = __builtin_bit_cast(half2v, b);
  return c + (float)av.x * (float)bv.x + (float)av.y * (float)bv.y;
#endif
}
__device__ __forceinline__ uint alignp(uint a, uint b) {  // {lo:b.hi, hi:a.lo}
  return __builtin_amdgcn_alignbit(a, b, 16);
}
__device__ __forceinline__ unsigned short f2h(float v) {
  return __builtin_bit_cast(unsigned short, (_Float16)v);
}
__device__ __forceinline__ uint getq(const uint4& v, int q) {
  return q == 0 ? v.x : q == 1 ? v.y : q == 2 ? v.z : v.w;
}

// ---- kernel 0: fp32 -> f16 streaming convert
__global__ __launch_bounds__(256) void cvt_f32_f16(const float* __restrict__ x,
                                                   unsigned short* __restrict__ xh,
                                                   int n4) {
  const int stride = gridDim.x * blockDim.x;
  for (int i = blockIdx.x * blockDim.x + threadIdx.x; i < n4; i += stride) {
    const float4 v = *reinterpret_cast<const float4*>(x + (size_t)i * 4);
    uint2 u; u.x = pkrtz(v.x, v.y); u.y = pkrtz(v.z, v.w);
    *reinterpret_cast<uint2*>(xh + (size_t)i * 4) = u;
  }
}

// ---- kernel 0b: pack g into f16 j-pair planes.
// gbuf uint index: ((b*5+i)*9 + p)*PLANE + h*WW + w, p = k*3+jp.
__global__ __launch_bounds__(256) void gpack(const float* __restrict__ g,
                                             uint* __restrict__ gbuf) {
  const int n4 = (int)(GPB_UINTS / 4);    // uint4 items
  const int stride = gridDim.x * blockDim.x;
  for (int it = blockIdx.x * blockDim.x + threadIdx.x; it < n4; it += stride) {
    const int w4 = (it % (PLANE / 4)) * 4;          // w of first uint
    const int rest = it / (PLANE / 4);              // (b*5+i)*9 + p
    const int p = rest % 9;
    const int bi = rest / 9;                        // b*5 + i
    const int i = bi % 5, b = bi / 5;
    const int k = p / 3, jp = p % 3;
    const int chA = (i * 5 + 2 * jp) * 3 + k;
    const float* gb = g + (size_t)b * GG * PLANE;
    const float4 a = *reinterpret_cast<const float4*>(gb + (size_t)chA * PLANE + w4);
    float4 bq = make_float4(0.f, 0.f, 0.f, 0.f);
    if (jp < 2)
      bq = *reinterpret_cast<const float4*>(gb + (size_t)(chA + 3) * PLANE + w4);
    uint4 u;
    u.x = pkrtz(a.x, bq.x); u.y = pkrtz(a.y, bq.y);
    u.z = pkrtz(a.z, bq.z); u.w = pkrtz(a.w, bq.w);
    *reinterpret_cast<uint4*>(gbuf + (size_t)it * 4) = u;
  }
}

// ---- the aggregation pass: f16 input, OT output (f16 or f32)
template <typename OT, bool PACKED>
__global__ __launch_bounds__(256) void lga_pass(const unsigned short* __restrict__ x,
                                                const float* __restrict__ g,
                                                const uint* __restrict__ gpk,
                                                OT* __restrict__ out) {
  __shared__ __align__(16) unsigned char xs[2][SROWS * ROWB];  // 19008 B
  __shared__ __align__(16) unsigned char gsl[9 * GPL];         // 9216 B

  // XCD-bijective swizzle; dch fastest, then h, c, b.
  constexpr int NWG = BB * CC * NCH * HH;   // 12288
  const int bx = blockIdx.x;
  const int lid = (bx & 7) * (NWG >> 3) + (bx >> 3);
  const int dch = lid % NCH;
  const int h   = (lid / NCH) % HH;
  const int c   = (lid / (NCH * HH)) % CC;
  const int b   =  lid / (NCH * HH * CC);

  const int tid = threadIdx.x;
  const int lane = tid & 63;
  const int dg = tid >> 6;                  // wave index (uniform)
  const int w0 = lane * WPT;
  const int d0 = dch * DCHUNK + dg * DPG;

  const unsigned short* xb = x + (size_t)(b * CC + c) * DD * PLANE;
  const float* gb = g + (size_t)b * GG * PLANE;

  // ---- zero init: per-row pads (both bufs) + out-of-range border depth rows
  if (tid < 2 * SROWS) {
    const int buf = tid / SROWS, s = tid % SROWS;
    unsigned char* r = &xs[buf][s * ROWB];
    *reinterpret_cast<uint*>(r) = 0;                           // w = -2,-1
    *reinterpret_cast<uint*>(r + 516) = 0;                     // w = 256,257
    *reinterpret_cast<uint2*>(r + 520) = make_uint2(0, 0);     // w = 258..261
  }
  constexpr int RDW = ROWB / 4;
  if (dch == 0)
    for (int idx = tid; idx < 2 * RDW; idx += 256)
      reinterpret_cast<uint*>(&xs[idx / RDW][0])[idx % RDW] = 0;
  if (dch == NCH - 1)
    for (int idx = tid; idx < 2 * RDW; idx += 256)
      reinterpret_cast<uint*>(&xs[idx / RDW][(SROWS - 1) * ROWB])[idx % RDW] = 0;

  float acc[DPG][WPT];
#pragma unroll
  for (int a = 0; a < DPG; ++a)
#pragma unroll
    for (int q = 0; q < WPT; ++q) acc[a][q] = 0.f;

  const int ilo = (h >= RAD) ? 0 : RAD - h;
  const int him = HH - 1 + RAD - h;
  const int ihi = (him < 4) ? him : 4;

  uint2 srl[5];      // x stage regs: 4 halves per row
  uint4 grg[3];      // g stage regs (PACKED path)
  float4 gra[3], grb[3];  // g stage regs (fallback path; DCE'd when PACKED)

  auto xstage_load = [&](int i) {
    const int hr = h + i - RAD;
#pragma unroll
    for (int t = 0; t < 5; ++t) {
      const int s = dg + NWV * t;
      if (s < SROWS &&
          !(s == 0 && dch == 0) && !(s == SROWS - 1 && dch == NCH - 1)) {
        const int dd = dch * DCHUNK + s - 1;
        srl[t] = *reinterpret_cast<const uint2*>(xb + (size_t)dd * PLANE + hr * WW + w0);
      }
    }
  };
  auto xstage_write = [&](int buf) {
#pragma unroll
    for (int t = 0; t < 5; ++t) {
      const int s = dg + NWV * t;
      if (s < SROWS &&
          !(s == 0 && dch == 0) && !(s == SROWS - 1 && dch == NCH - 1)) {
        unsigned char* rp = &xs[buf][s * ROWB + 4 + 8 * lane];  // core @ w0
        *reinterpret_cast<uint*>(rp) = srl[t].x;
        *reinterpret_cast<uint*>(rp + 4) = srl[t].y;
      }
    }
  };

  // g stage, split: load into regs (issued before compute), write after.
  // items: r=0,1 for all threads; r=2 only tid<64.  (9 planes x 64 slots)
  auto gstage_load = [&](int i) {
#pragma unroll
    for (int r = 0; r < 3; ++r) {
      const int item = tid + (r << 8);
      if (item < 576) {
        const int p = item >> 6, slot = item & 63;
        if constexpr (PACKED) {
          grg[r] = *reinterpret_cast<const uint4*>(
              gpk + ((size_t)((b * 5 + i) * 9 + p)) * PLANE + h * WW + 4 * slot);
        } else {
          const int k = p / 3, jp = p % 3;
          const int chA = (i * 5 + 2 * jp) * 3 + k;
          gra[r] = *reinterpret_cast<const float4*>(
              gb + (size_t)chA * PLANE + h * WW + 4 * slot);
          grb[r] = make_float4(0.f, 0.f, 0.f, 0.f);
          if (jp < 2)
            grb[r] = *reinterpret_cast<const float4*>(
                gb + (size_t)(chA + 3) * PLANE + h * WW + 4 * slot);
        }
      }
    }
  };
  auto gstage_write = [&]() {
#pragma unroll
    for (int r = 0; r < 3; ++r) {
      const int item = tid + (r << 8);
      if (item < 576) {
        const int p = item >> 6, slot = item & 63;
        uint4 u;
        if constexpr (PACKED) {
          u = grg[r];
        } else {
          u.x = pkrtz(gra[r].x, grb[r].x); u.y = pkrtz(gra[r].y, grb[r].y);
          u.z = pkrtz(gra[r].z, grb[r].z); u.w = pkrtz(gra[r].w, grb[r].w);
        }
        *reinterpret_cast<uint4*>(&gsl[p * GPL + 16 * slot]) = u;
      }
    }
  };

  int cur = 0;
  gstage_load(ilo);
  xstage_load(ilo);
  gstage_write();
  xstage_write(0);
  __syncthreads();

  for (int ii = ilo; ii <= ihi; ++ii) {
    // G pairs for this tap: plane p, pixels w0..w0+3 (16B/lane). LDS-only.
    uint4 G[9];
#pragma unroll
    for (int p = 0; p < 9; ++p)
      G[p] = *reinterpret_cast<const uint4*>(&gsl[p * GPL + 16 * lane]);

    // Mid barrier with NOTHING vmem outstanding -> its vmcnt(0) is free.
    __syncthreads();

    // Issue ALL next-tap loads now; compute below hides their latency.
    if (ii < ihi) {
      gstage_load(ii + 1);
      xstage_load(ii + 1);
    }

    const unsigned char* wb = &xs[cur][(dg * DPG) * ROWB] + 8 * lane;
#pragma unroll
    for (int a = -1; a <= DPG; ++a) {       // slab rows d0-1 .. d0+4
      const unsigned char* rp = wb + (a + 1) * ROWB;
      const uint2 e01 = *reinterpret_cast<const uint2*>(rp);
      const uint2 e23 = *reinterpret_cast<const uint2*>(rp + 8);
      const uint  e4  = *reinterpret_cast<const uint*>(rp + 16);
      uint P[9];
      P[0] = e01.x; P[2] = e01.y; P[4] = e23.x; P[6] = e23.y; P[8] = e4;
      P[1] = alignp(P[2], P[0]);
      P[3] = alignp(P[4], P[2]);
      P[5] = alignp(P[6], P[4]);
      P[7] = alignp(P[8], P[6]);
#pragma unroll
      for (int k = 0; k < 3; ++k) {
        const int ai = a + 1 - k;
        if (ai < 0 || ai >= DPG) continue;  // compile-time
#pragma unroll
        for (int q = 0; q < WPT; ++q) {
          float t = acc[ai][q];
          t = fdot2(getq(G[k * 3 + 0], q), P[q], t);
          t = fdot2(getq(G[k * 3 + 1], q), P[q + 2], t);
          t = fdot2(getq(G[k * 3 + 2], q), P[q + 4], t);
          acc[ai][q] = t;
        }
      }
    }
    // Writes: the loads arrived during compute -> vmcnt waits are short.
    if (ii < ihi) {
      gstage_write();
      xstage_write(cur ^ 1);
    }
    __syncthreads();
    cur ^= 1;
  }

  const int obase = d0 * PLANE + h * WW + w0;
  if constexpr (sizeof(OT) == 4) {
    float* ob = (float*)out + (size_t)(b * CC + c) * DD * PLANE;
#pragma unroll
    for (int ai = 0; ai < DPG; ++ai) {
      float4 t; t.x = acc[ai][0]; t.y = acc[ai][1]; t.z = acc[ai][2]; t.w = acc[ai][3];
      *reinterpret_cast<float4*>(ob + obase + ai * PLANE) = t;
    }
  } else {
    unsigned short* ob = (unsigned short*)out + (size_t)(b * CC + c) * DD * PLANE;
#pragma unroll
    for (int ai = 0; ai < DPG; ++ai) {
      ushort4 t; t.x = f2h(acc[ai][0]); t.y = f2h(acc[ai][1]);
      t.z = f2h(acc[ai][2]); t.w = f2h(acc[ai][3]);
      *reinterpret_cast<ushort4*>(ob + obase + ai * PLANE) = t;
    }
  }
}

extern "C" void kernel_launch(void* const* d_in, const int* in_sizes, int n_in,
                              void* d_out, int out_size, void* d_ws, size_t ws_size,
                              hipStream_t stream) {
  const float* x = (const float*)d_in[0];
  const float* g = (const float*)d_in[1];
  float* out = (float*)d_out;

  const size_t elems = (size_t)BB * CC * DD * HH * WW;   // 50,331,648
  // xh (f16) borrows d_out's first 100.6MB; y (f16) at d_ws start.
  // Pass2 reads only d_ws (y + optional gpk) and overwrites d_out.
  unsigned short* xh = (unsigned short*)d_out;
  unsigned short* y  = (unsigned short*)d_ws;

  cvt_f32_f16<<<2048, 256, 0, stream>>>(x, xh, (int)(elems / 4));

  const dim3 grid(BB * CC * NCH * HH);   // 12288
  const dim3 block(64 * NWV);            // 256

  // Packed-G buffer lives after y in d_ws if it fits (y:100.6MB + gpk:11.8MB).
  const size_t need = elems * 2 + GPB_UINTS * 4;
  if (ws_size >= need) {
    uint* gbuf = (uint*)((char*)d_ws + elems * 2);
    gpack<<<1440, 256, 0, stream>>>(g, gbuf);
    lga_pass<unsigned short, true><<<grid, block, 0, stream>>>(xh, g, gbuf, y);
    lga_pass<float, true><<<grid, block, 0, stream>>>(y, g, gbuf, out);
  } else {
    lga_pass<unsigned short, false><<<grid, block, 0, stream>>>(xh, g, nullptr, y);
    lga_pass<float, false><<<grid, block, 0, stream>>>(y, g, nullptr, out);
  }
}

// Round 17
// 355.569 us; speedup vs baseline: 1.1928x; 1.0385x over previous
//
#include <hip/hip_runtime.h>
#include <hip/hip_bf16.h>

// LGA3D2: out = A_g(A_g(x)); A_g is a 5x5 spatial x 3-depth guided aggregation.
// out[b,c,d,h,w] = sum_{i,j in 5x5, k in 0..2} g[b,(i*5+j)*3+k,h,w] * x[b,c,d+k-1,h+i-2,w+j-2]
// x: [B,C,D,H,W] fp32, g: [B,75,H,W] fp32.
//
// R17 = R16 minus the G LDS round-trip:
//   gsl was a pure copy of gpk; each lane's LDS G-read maps 1:1 to a
//   coalesced global read of gpk (L1/L2-resident, 4 waves broadcast-share).
//   -> load G[9] per wave straight from global. Removes 9 b128 LDS reads
//   per lane + all g ds_writes per tap (-33% LDS-pipe instrs), the whole
//   gstage, and the mid barrier (2 -> 1 barriers/tap). LDS 28.7 -> 19.0 KB
//   -> 8 blocks/CU ceiling for TLP.
//   Issue order per tap: G loads (oldest, consumed first) -> next-tap x
//   loads (newer, stay in flight under compute) -> compute -> x write ->
//   single barrier.

constexpr int RAD = 2;
constexpr int BB = 2, CC = 16, DD = 48, HH = 128, WW = 256;
constexpr int GG = 75;
constexpr int PLANE = HH * WW;

constexpr int WPT = 4;            // outputs per lane along W
constexpr int DPG = 4;            // depths per wave
constexpr int NWV = 4;            // waves per block
constexpr int DCHUNK = 16;        // depths per block
constexpr int NCH = DD / DCHUNK;  // 3
constexpr int SROWS = DCHUNK + 2; // 18 slab rows (d-1 .. d+16)
constexpr int ROWB = 528;         // f16 x-slab row bytes: [4][512][12]
constexpr size_t GPB_UINTS = (size_t)BB * 5 * 9 * PLANE;   // packed G uints

using uint = unsigned int;
typedef __attribute__((ext_vector_type(2))) _Float16 half2v;

__device__ __forceinline__ uint pkrtz(float a, float b) {
  return __builtin_bit_cast(uint, __builtin_amdgcn_cvt_pkrtz(a, b));
}
__device__ __forceinline__ float fdot2(uint a, uint b, float c) {
#if __has_builtin(__builtin_amdgcn_fdot2)
  return __builtin_amdgcn_fdot2(__builtin_bit_cast(half2v, a),
                                __builtin_bit_cast(half2v, b), c, false);
#else
  half2v av = __builtin_bit_cast(half2v, a), bv = __builtin_bit_cast(half2v, b);
  return c + (float)av.x * (float)bv.x + (float)av.y * (float)bv.y;
#endif
}
__device__ __forceinline__ uint alignp(uint a, uint b) {  // {lo:b.hi, hi:a.lo}
  return __builtin_amdgcn_alignbit(a, b, 16);
}
__device__ __forceinline__ unsigned short f2h(float v) {
  return __builtin_bit_cast(unsigned short, (_Float16)v);
}
__device__ __forceinline__ uint getq(const uint4& v, int q) {
  return q == 0 ? v.x : q == 1 ? v.y : q == 2 ? v.z : v.w;
}

// ---- kernel 0: fp32 -> f16 streaming convert
__global__ __launch_bounds__(256) void cvt_f32_f16(const float* __restrict__ x,
                                                   unsigned short* __restrict__ xh,
                                                   int n4) {
  const int stride = gridDim.x * blockDim.x;
  for (int i = blockIdx.x * blockDim.x + threadIdx.x; i < n4; i += stride) {
    const float4 v = *reinterpret_cast<const float4*>(x + (size_t)i * 4);
    uint2 u; u.x = pkrtz(v.x, v.y); u.y = pkrtz(v.z, v.w);
    *reinterpret_cast<uint2*>(xh + (size_t)i * 4) = u;
  }
}

// ---- kernel 0b: pack g into f16 j-pair planes.
// gbuf uint index: ((b*5+i)*9 + p)*PLANE + h*WW + w, p = k*3+jp.
// value = {f16 g[(i*5+2jp)*3+k], f16 g[(i*5+2jp+1)*3+k] or 0} at (h,w).
__global__ __launch_bounds__(256) void gpack(const float* __restrict__ g,
                                             uint* __restrict__ gbuf) {
  const int n4 = (int)(GPB_UINTS / 4);    // uint4 items
  const int stride = gridDim.x * blockDim.x;
  for (int it = blockIdx.x * blockDim.x + threadIdx.x; it < n4; it += stride) {
    const int w4 = (it % (PLANE / 4)) * 4;          // w of first uint
    const int rest = it / (PLANE / 4);              // (b*5+i)*9 + p
    const int p = rest % 9;
    const int bi = rest / 9;                        // b*5 + i
    const int i = bi % 5, b = bi / 5;
    const int k = p / 3, jp = p % 3;
    const int chA = (i * 5 + 2 * jp) * 3 + k;
    const float* gb = g + (size_t)b * GG * PLANE;
    const float4 a = *reinterpret_cast<const float4*>(gb + (size_t)chA * PLANE + w4);
    float4 bq = make_float4(0.f, 0.f, 0.f, 0.f);
    if (jp < 2)
      bq = *reinterpret_cast<const float4*>(gb + (size_t)(chA + 3) * PLANE + w4);
    uint4 u;
    u.x = pkrtz(a.x, bq.x); u.y = pkrtz(a.y, bq.y);
    u.z = pkrtz(a.z, bq.z); u.w = pkrtz(a.w, bq.w);
    *reinterpret_cast<uint4*>(gbuf + (size_t)it * 4) = u;
  }
}

// ---- the aggregation pass: f16 input, OT output (f16 or f32)
template <typename OT, bool PACKED>
__global__ __launch_bounds__(256) void lga_pass(const unsigned short* __restrict__ x,
                                                const float* __restrict__ g,
                                                const uint* __restrict__ gpk,
                                                OT* __restrict__ out) {
  __shared__ __align__(16) unsigned char xs[2][SROWS * ROWB];  // 19008 B only

  // XCD-bijective swizzle; dch fastest, then h, c, b.
  constexpr int NWG = BB * CC * NCH * HH;   // 12288
  const int bx = blockIdx.x;
  const int lid = (bx & 7) * (NWG >> 3) + (bx >> 3);
  const int dch = lid % NCH;
  const int h   = (lid / NCH) % HH;
  const int c   = (lid / (NCH * HH)) % CC;
  const int b   =  lid / (NCH * HH * CC);

  const int tid = threadIdx.x;
  const int lane = tid & 63;
  const int dg = tid >> 6;                  // wave index (uniform)
  const int w0 = lane * WPT;
  const int d0 = dch * DCHUNK + dg * DPG;

  const unsigned short* xb = x + (size_t)(b * CC + c) * DD * PLANE;
  const float* gb = g + (size_t)b * GG * PLANE;

  // ---- zero init: per-row pads (both bufs) + out-of-range border depth rows
  if (tid < 2 * SROWS) {
    const int buf = tid / SROWS, s = tid % SROWS;
    unsigned char* r = &xs[buf][s * ROWB];
    *reinterpret_cast<uint*>(r) = 0;                           // w = -2,-1
    *reinterpret_cast<uint*>(r + 516) = 0;                     // w = 256,257
    *reinterpret_cast<uint2*>(r + 520) = make_uint2(0, 0);     // w = 258..261
  }
  constexpr int RDW = ROWB / 4;
  if (dch == 0)
    for (int idx = tid; idx < 2 * RDW; idx += 256)
      reinterpret_cast<uint*>(&xs[idx / RDW][0])[idx % RDW] = 0;
  if (dch == NCH - 1)
    for (int idx = tid; idx < 2 * RDW; idx += 256)
      reinterpret_cast<uint*>(&xs[idx / RDW][(SROWS - 1) * ROWB])[idx % RDW] = 0;

  float acc[DPG][WPT];
#pragma unroll
  for (int a = 0; a < DPG; ++a)
#pragma unroll
    for (int q = 0; q < WPT; ++q) acc[a][q] = 0.f;

  const int ilo = (h >= RAD) ? 0 : RAD - h;
  const int him = HH - 1 + RAD - h;
  const int ihi = (him < 4) ? him : 4;

  uint2 srl[5];      // x stage regs: 4 halves per row

  auto xstage_load = [&](int i) {
    const int hr = h + i - RAD;
#pragma unroll
    for (int t = 0; t < 5; ++t) {
      const int s = dg + NWV * t;
      if (s < SROWS &&
          !(s == 0 && dch == 0) && !(s == SROWS - 1 && dch == NCH - 1)) {
        const int dd = dch * DCHUNK + s - 1;
        srl[t] = *reinterpret_cast<const uint2*>(xb + (size_t)dd * PLANE + hr * WW + w0);
      }
    }
  };
  auto xstage_write = [&](int buf) {
#pragma unroll
    for (int t = 0; t < 5; ++t) {
      const int s = dg + NWV * t;
      if (s < SROWS &&
          !(s == 0 && dch == 0) && !(s == SROWS - 1 && dch == NCH - 1)) {
        unsigned char* rp = &xs[buf][s * ROWB + 4 + 8 * lane];  // core @ w0
        *reinterpret_cast<uint*>(rp) = srl[t].x;
        *reinterpret_cast<uint*>(rp + 4) = srl[t].y;
      }
    }
  };

  int cur = 0;
  xstage_load(ilo);
  xstage_write(0);
  __syncthreads();

  for (int ii = ilo; ii <= ihi; ++ii) {
    // G[9] for this tap, straight from global (issued FIRST = oldest vmem,
    // consumed first; the x loads below stay in flight under compute).
    uint4 G[9];
    if constexpr (PACKED) {
      const uint* gp = gpk + ((size_t)(b * 5 + ii) * 9) * PLANE + h * WW + w0;
#pragma unroll
      for (int p = 0; p < 9; ++p)
        G[p] = *reinterpret_cast<const uint4*>(gp + (size_t)p * PLANE);
    } else {
      // fallback: build G from raw g in-registers (no LDS), 18 float4 loads
#pragma unroll
      for (int k = 0; k < 3; ++k)
#pragma unroll
        for (int jp = 0; jp < 3; ++jp) {
          const int chA = (ii * 5 + 2 * jp) * 3 + k;
          const float4 a = *reinterpret_cast<const float4*>(
              gb + (size_t)chA * PLANE + h * WW + w0);
          float4 bq = make_float4(0.f, 0.f, 0.f, 0.f);
          if (jp < 2)
            bq = *reinterpret_cast<const float4*>(
                gb + (size_t)(chA + 3) * PLANE + h * WW + w0);
          uint4 u;
          u.x = pkrtz(a.x, bq.x); u.y = pkrtz(a.y, bq.y);
          u.z = pkrtz(a.z, bq.z); u.w = pkrtz(a.w, bq.w);
          G[k * 3 + jp] = u;
        }
    }

    if (ii < ihi) xstage_load(ii + 1);      // newer vmem; in flight past G use

    const unsigned char* wb = &xs[cur][(dg * DPG) * ROWB] + 8 * lane;
#pragma unroll
    for (int a = -1; a <= DPG; ++a) {       // slab rows d0-1 .. d0+4
      const unsigned char* rp = wb + (a + 1) * ROWB;
      const uint2 e01 = *reinterpret_cast<const uint2*>(rp);
      const uint2 e23 = *reinterpret_cast<const uint2*>(rp + 8);
      const uint  e4  = *reinterpret_cast<const uint*>(rp + 16);
      uint P[9];
      P[0] = e01.x; P[2] = e01.y; P[4] = e23.x; P[6] = e23.y; P[8] = e4;
      P[1] = alignp(P[2], P[0]);
      P[3] = alignp(P[4], P[2]);
      P[5] = alignp(P[6], P[4]);
      P[7] = alignp(P[8], P[6]);
#pragma unroll
      for (int k = 0; k < 3; ++k) {
        const int ai = a + 1 - k;
        if (ai < 0 || ai >= DPG) continue;  // compile-time
#pragma unroll
        for (int q = 0; q < WPT; ++q) {
          float t = acc[ai][q];
          t = fdot2(getq(G[k * 3 + 0], q), P[q], t);
          t = fdot2(getq(G[k * 3 + 1], q), P[q + 2], t);
          t = fdot2(getq(G[k * 3 + 2], q), P[q + 4], t);
          acc[ai][q] = t;
        }
      }
    }
    if (ii < ihi) xstage_write(cur ^ 1);    // x loads arrived during compute
    __syncthreads();                        // single barrier per tap
    cur ^= 1;
  }

  const int obase = d0 * PLANE + h * WW + w0;
  if constexpr (sizeof(OT) == 4) {
    float* ob = (float*)out + (size_t)(b * CC + c) * DD * PLANE;
#pragma unroll
    for (int ai = 0; ai < DPG; ++ai) {
      float4 t; t.x = acc[ai][0]; t.y = acc[ai][1]; t.z = acc[ai][2]; t.w = acc[ai][3];
      *reinterpret_cast<float4*>(ob + obase + ai * PLANE) = t;
    }
  } else {
    unsigned short* ob = (unsigned short*)out + (size_t)(b * CC + c) * DD * PLANE;
#pragma unroll
    for (int ai = 0; ai < DPG; ++ai) {
      ushort4 t; t.x = f2h(acc[ai][0]); t.y = f2h(acc[ai][1]);
      t.z = f2h(acc[ai][2]); t.w = f2h(acc[ai][3]);
      *reinterpret_cast<ushort4*>(ob + obase + ai * PLANE) = t;
    }
  }
}

extern "C" void kernel_launch(void* const* d_in, const int* in_sizes, int n_in,
                              void* d_out, int out_size, void* d_ws, size_t ws_size,
                              hipStream_t stream) {
  const float* x = (const float*)d_in[0];
  const float* g = (const float*)d_in[1];
  float* out = (float*)d_out;

  const size_t elems = (size_t)BB * CC * DD * HH * WW;   // 50,331,648
  // xh (f16) borrows d_out's first 100.6MB; y (f16) at d_ws start.
  // Pass2 reads only d_ws (y + gpk) and overwrites d_out.
  unsigned short* xh = (unsigned short*)d_out;
  unsigned short* y  = (unsigned short*)d_ws;

  cvt_f32_f16<<<2048, 256, 0, stream>>>(x, xh, (int)(elems / 4));

  const dim3 grid(BB * CC * NCH * HH);   // 12288
  const dim3 block(64 * NWV);            // 256

  // Packed-G buffer lives after y in d_ws if it fits (y:100.6MB + gpk:11.8MB).
  const size_t need = elems * 2 + GPB_UINTS * 4;
  if (ws_size >= need) {
    uint* gbuf = (uint*)((char*)d_ws + elems * 2);
    gpack<<<1440, 256, 0, stream>>>(g, gbuf);
    lga_pass<unsigned short, true><<<grid, block, 0, stream>>>(xh, g, gbuf, y);
    lga_pass<float, true><<<grid, block, 0, stream>>>(y, g, gbuf, out);
  } else {
    lga_pass<unsigned short, false><<<grid, block, 0, stream>>>(xh, g, nullptr, y);
    lga_pass<float, false><<<grid, block, 0, stream>>>(y, g, nullptr, out);
  }
}

// Round 18
// 355.341 us; speedup vs baseline: 1.1935x; 1.0006x over previous
//
#include <hip/hip_runtime.h>
#include <hip/hip_bf16.h>

// LGA3D2: out = A_g(A_g(x)); A_g is a 5x5 spatial x 3-depth guided aggregation.
// out[b,c,d,h,w] = sum_{i,j in 5x5, k in 0..2} g[b,(i*5+j)*3+k,h,w] * x[b,c,d+k-1,h+i-2,w+j-2]
// x: [B,C,D,H,W] fp32, g: [B,75,H,W] fp32.
//
// R18 = R17 minus the x LDS slab. The slab existed only to give each lane
// its +-2 w-neighbors; ds_bpermute provides that without storage or sync:
//   per depth-row: own aligned uint2 global load (4 halves, L1/L2-served)
//   + 3 ds_bpermute (shift by one lane) + 3 cndmask (W-boundary zeros)
//   + 4 alignbit -> the 9-uint window. Depth-border rows (wave-uniform)
//   skip the load -> zeros propagate.
// Removes ALL ds_read/ds_write, the double-buffer, the zero-init, and every
// __syncthreads (no shared state): waves free-run; LDS=0 so occupancy is
// VGPR-limited only. G stays direct-from-gpk (R17).

constexpr int RAD = 2;
constexpr int BB = 2, CC = 16, DD = 48, HH = 128, WW = 256;
constexpr int GG = 75;
constexpr int PLANE = HH * WW;

constexpr int WPT = 4;            // outputs per lane along W
constexpr int DPG = 4;            // depths per wave
constexpr int NWV = 4;            // waves per block
constexpr int DCHUNK = 16;        // depths per block
constexpr int NCH = DD / DCHUNK;  // 3
constexpr size_t GPB_UINTS = (size_t)BB * 5 * 9 * PLANE;   // packed G uints

using uint = unsigned int;
typedef __attribute__((ext_vector_type(2))) _Float16 half2v;

__device__ __forceinline__ uint pkrtz(float a, float b) {
  return __builtin_bit_cast(uint, __builtin_amdgcn_cvt_pkrtz(a, b));
}
__device__ __forceinline__ float fdot2(uint a, uint b, float c) {
#if __has_builtin(__builtin_amdgcn_fdot2)
  return __builtin_amdgcn_fdot2(__builtin_bit_cast(half2v, a),
                                __builtin_bit_cast(half2v, b), c, false);
#else
  half2v av = __builtin_bit_cast(half2v, a), bv = __builtin_bit_cast(half2v, b);
  return c + (float)av.x * (float)bv.x + (float)av.y * (float)bv.y;
#endif
}
__device__ __forceinline__ uint alignp(uint a, uint b) {  // {lo:b.hi, hi:a.lo}
  return __builtin_amdgcn_alignbit(a, b, 16);
}
__device__ __forceinline__ unsigned short f2h(float v) {
  return __builtin_bit_cast(unsigned short, (_Float16)v);
}
__device__ __forceinline__ uint getq(const uint4& v, int q) {
  return q == 0 ? v.x : q == 1 ? v.y : q == 2 ? v.z : v.w;
}

// ---- kernel 0: fp32 -> f16 streaming convert
__global__ __launch_bounds__(256) void cvt_f32_f16(const float* __restrict__ x,
                                                   unsigned short* __restrict__ xh,
                                                   int n4) {
  const int stride = gridDim.x * blockDim.x;
  for (int i = blockIdx.x * blockDim.x + threadIdx.x; i < n4; i += stride) {
    const float4 v = *reinterpret_cast<const float4*>(x + (size_t)i * 4);
    uint2 u; u.x = pkrtz(v.x, v.y); u.y = pkrtz(v.z, v.w);
    *reinterpret_cast<uint2*>(xh + (size_t)i * 4) = u;
  }
}

// ---- kernel 0b: pack g into f16 j-pair planes.
// gbuf uint index: ((b*5+i)*9 + p)*PLANE + h*WW + w, p = k*3+jp.
// value = {f16 g[(i*5+2jp)*3+k], f16 g[(i*5+2jp+1)*3+k] or 0} at (h,w).
__global__ __launch_bounds__(256) void gpack(const float* __restrict__ g,
                                             uint* __restrict__ gbuf) {
  const int n4 = (int)(GPB_UINTS / 4);    // uint4 items
  const int stride = gridDim.x * blockDim.x;
  for (int it = blockIdx.x * blockDim.x + threadIdx.x; it < n4; it += stride) {
    const int w4 = (it % (PLANE / 4)) * 4;          // w of first uint
    const int rest = it / (PLANE / 4);              // (b*5+i)*9 + p
    const int p = rest % 9;
    const int bi = rest / 9;                        // b*5 + i
    const int i = bi % 5, b = bi / 5;
    const int k = p / 3, jp = p % 3;
    const int chA = (i * 5 + 2 * jp) * 3 + k;
    const float* gb = g + (size_t)b * GG * PLANE;
    const float4 a = *reinterpret_cast<const float4*>(gb + (size_t)chA * PLANE + w4);
    float4 bq = make_float4(0.f, 0.f, 0.f, 0.f);
    if (jp < 2)
      bq = *reinterpret_cast<const float4*>(gb + (size_t)(chA + 3) * PLANE + w4);
    uint4 u;
    u.x = pkrtz(a.x, bq.x); u.y = pkrtz(a.y, bq.y);
    u.z = pkrtz(a.z, bq.z); u.w = pkrtz(a.w, bq.w);
    *reinterpret_cast<uint4*>(gbuf + (size_t)it * 4) = u;
  }
}

// ---- the aggregation pass: f16 input, OT output (f16 or f32)
template <typename OT, bool PACKED>
__global__ __launch_bounds__(256) void lga_pass(const unsigned short* __restrict__ x,
                                                const float* __restrict__ g,
                                                const uint* __restrict__ gpk,
                                                OT* __restrict__ out) {
  // XCD-bijective swizzle; dch fastest, then h, c, b.
  constexpr int NWG = BB * CC * NCH * HH;   // 12288
  const int bx = blockIdx.x;
  const int lid = (bx & 7) * (NWG >> 3) + (bx >> 3);
  const int dch = lid % NCH;
  const int h   = (lid / NCH) % HH;
  const int c   = (lid / (NCH * HH)) % CC;
  const int b   =  lid / (NCH * HH * CC);

  const int tid = threadIdx.x;
  const int lane = tid & 63;
  const int dg = tid >> 6;                  // wave index (uniform)
  const int w0 = lane * WPT;
  const int d0 = dch * DCHUNK + dg * DPG;

  const unsigned short* xb = x + (size_t)(b * CC + c) * DD * PLANE;
  const float* gb = g + (size_t)b * GG * PLANE;

  // bpermute byte indices (hoisted)
  const int lm1 = ((lane - 1) & 63) * 4;
  const int lp1 = ((lane + 1) & 63) * 4;
  const bool l0 = (lane == 0);
  const bool l63 = (lane == 63);

  float acc[DPG][WPT];
#pragma unroll
  for (int a = 0; a < DPG; ++a)
#pragma unroll
    for (int q = 0; q < WPT; ++q) acc[a][q] = 0.f;

  const int ilo = (h >= RAD) ? 0 : RAD - h;
  const int him = HH - 1 + RAD - h;
  const int ihi = (him < 4) ? him : 4;

  for (int ii = ilo; ii <= ihi; ++ii) {
    const int hr = h + ii - RAD;

    // G[9] for this tap, straight from global (L1/L2-resident; 4 waves share)
    uint4 G[9];
    if constexpr (PACKED) {
      const uint* gp = gpk + ((size_t)(b * 5 + ii) * 9) * PLANE + h * WW + w0;
#pragma unroll
      for (int p = 0; p < 9; ++p)
        G[p] = *reinterpret_cast<const uint4*>(gp + (size_t)p * PLANE);
    } else {
#pragma unroll
      for (int k = 0; k < 3; ++k)
#pragma unroll
        for (int jp = 0; jp < 3; ++jp) {
          const int chA = (ii * 5 + 2 * jp) * 3 + k;
          const float4 a = *reinterpret_cast<const float4*>(
              gb + (size_t)chA * PLANE + h * WW + w0);
          float4 bq = make_float4(0.f, 0.f, 0.f, 0.f);
          if (jp < 2)
            bq = *reinterpret_cast<const float4*>(
                gb + (size_t)(chA + 3) * PLANE + h * WW + w0);
          uint4 u;
          u.x = pkrtz(a.x, bq.x); u.y = pkrtz(a.y, bq.y);
          u.z = pkrtz(a.z, bq.z); u.w = pkrtz(a.w, bq.w);
          G[k * 3 + jp] = u;
        }
    }

#pragma unroll
    for (int a = -1; a <= DPG; ++a) {       // x depth rows d0-1 .. d0+4
      bool dok = true;
      if (a == -1)  dok = (d0 > 0);         // wave-uniform depth zero-pad
      if (a == DPG) dok = (d0 + DPG < DD);

      uint2 own = make_uint2(0u, 0u);       // 4 halves: w0 .. w0+3
      if (dok)
        own = *reinterpret_cast<const uint2*>(
            xb + (size_t)(d0 + a) * PLANE + hr * WW + w0);

      // 9-uint window P[m] = {w0-2+2m, w0-1+2m} via cross-lane shuffle
      const uint lft = __builtin_amdgcn_ds_bpermute(lm1, (int)own.y);
      const uint rg0 = __builtin_amdgcn_ds_bpermute(lp1, (int)own.x);
      const uint rg1 = __builtin_amdgcn_ds_bpermute(lp1, (int)own.y);
      uint P[9];
      P[0] = l0 ? 0u : lft;                 // {w0-2, w0-1}
      P[2] = own.x; P[4] = own.y;
      P[6] = l63 ? 0u : rg0;                // {w0+4, w0+5}
      P[8] = l63 ? 0u : rg1;                // {w0+6, w0+7} (x*G_pad0 only)
      P[1] = alignp(P[2], P[0]);
      P[3] = alignp(P[4], P[2]);
      P[5] = alignp(P[6], P[4]);
      P[7] = alignp(P[8], P[6]);

      // scatter: x row d0+a feeds acc[a+1-k]; per (k,ai,q): 3 dot2
#pragma unroll
      for (int k = 0; k < 3; ++k) {
        const int ai = a + 1 - k;
        if (ai < 0 || ai >= DPG) continue;  // compile-time
#pragma unroll
        for (int q = 0; q < WPT; ++q) {
          float t = acc[ai][q];
          t = fdot2(getq(G[k * 3 + 0], q), P[q], t);
          t = fdot2(getq(G[k * 3 + 1], q), P[q + 2], t);
          t = fdot2(getq(G[k * 3 + 2], q), P[q + 4], t);
          acc[ai][q] = t;
        }
      }
    }
  }

  const int obase = d0 * PLANE + h * WW + w0;
  if constexpr (sizeof(OT) == 4) {
    float* ob = (float*)out + (size_t)(b * CC + c) * DD * PLANE;
#pragma unroll
    for (int ai = 0; ai < DPG; ++ai) {
      float4 t; t.x = acc[ai][0]; t.y = acc[ai][1]; t.z = acc[ai][2]; t.w = acc[ai][3];
      *reinterpret_cast<float4*>(ob + obase + ai * PLANE) = t;
    }
  } else {
    unsigned short* ob = (unsigned short*)out + (size_t)(b * CC + c) * DD * PLANE;
#pragma unroll
    for (int ai = 0; ai < DPG; ++ai) {
      ushort4 t; t.x = f2h(acc[ai][0]); t.y = f2h(acc[ai][1]);
      t.z = f2h(acc[ai][2]); t.w = f2h(acc[ai][3]);
      *reinterpret_cast<ushort4*>(ob + obase + ai * PLANE) = t;
    }
  }
}

extern "C" void kernel_launch(void* const* d_in, const int* in_sizes, int n_in,
                              void* d_out, int out_size, void* d_ws, size_t ws_size,
                              hipStream_t stream) {
  const float* x = (const float*)d_in[0];
  const float* g = (const float*)d_in[1];
  float* out = (float*)d_out;

  const size_t elems = (size_t)BB * CC * DD * HH * WW;   // 50,331,648
  // xh (f16) borrows d_out's first 100.6MB; y (f16) at d_ws start.
  // Pass2 reads only d_ws (y + gpk) and overwrites d_out.
  unsigned short* xh = (unsigned short*)d_out;
  unsigned short* y  = (unsigned short*)d_ws;

  cvt_f32_f16<<<2048, 256, 0, stream>>>(x, xh, (int)(elems / 4));

  const dim3 grid(BB * CC * NCH * HH);   // 12288
  const dim3 block(64 * NWV);            // 256

  // Packed-G buffer lives after y in d_ws if it fits (y:100.6MB + gpk:11.8MB).
  const size_t need = elems * 2 + GPB_UINTS * 4;
  if (ws_size >= need) {
    uint* gbuf = (uint*)((char*)d_ws + elems * 2);
    gpack<<<1440, 256, 0, stream>>>(g, gbuf);
    lga_pass<unsigned short, true><<<grid, block, 0, stream>>>(xh, g, gbuf, y);
    lga_pass<float, true><<<grid, block, 0, stream>>>(y, g, gbuf, out);
  } else {
    lga_pass<unsigned short, false><<<grid, block, 0, stream>>>(xh, g, nullptr, y);
    lga_pass<float, false><<<grid, block, 0, stream>>>(y, g, nullptr, out);
  }
}

// Round 19
// 348.026 us; speedup vs baseline: 1.2186x; 1.0210x over previous
//
#include <hip/hip_runtime.h>
#include <hip/hip_bf16.h>

// LGA3D2: out = A_g(A_g(x)); A_g is a 5x5 spatial x 3-depth guided aggregation.
// out[b,c,d,h,w] = sum_{i,j in 5x5, k in 0..2} g[b,(i*5+j)*3+k,h,w] * x[b,c,d+k-1,h+i-2,w+j-2]
// x: [B,C,D,H,W] fp32, g: [B,75,H,W] fp32.
//
// R19 = R18 (bpermute window, no LDS, no barriers, G direct from packed
// buffer) with G cost amortized & coalesced:
//  - DPG 4 -> 6 (DCHUNK 24, NCH 2): the 9 G uint4 loads per wave-tap now
//    serve 24 outputs (-33% G L1 traffic + addressing). dot2/output same.
//  - gpk layout -> tap-contiguous [b][i][h][w/4][p][16B]: each lane's 9 G
//    uint4s are 144 CONTIGUOUS bytes (1 base + imm offsets) instead of 9
//    loads at 128KB stride; wave reads 9216B sequential.

constexpr int RAD = 2;
constexpr int BB = 2, CC = 16, DD = 48, HH = 128, WW = 256;
constexpr int GG = 75;
constexpr int PLANE = HH * WW;

constexpr int WPT = 4;            // outputs per lane along W
constexpr int DPG = 6;            // depths per wave
constexpr int NWV = 4;            // waves per block
constexpr int DCHUNK = DPG * NWV; // 24 depths per block
constexpr int NCH = DD / DCHUNK;  // 2
constexpr size_t GPB_UINTS = (size_t)BB * 5 * 9 * PLANE;   // packed G uints

using uint = unsigned int;
typedef __attribute__((ext_vector_type(2))) _Float16 half2v;

__device__ __forceinline__ uint pkrtz(float a, float b) {
  return __builtin_bit_cast(uint, __builtin_amdgcn_cvt_pkrtz(a, b));
}
__device__ __forceinline__ float fdot2(uint a, uint b, float c) {
#if __has_builtin(__builtin_amdgcn_fdot2)
  return __builtin_amdgcn_fdot2(__builtin_bit_cast(half2v, a),
                                __builtin_bit_cast(half2v, b), c, false);
#else
  half2v av = __builtin_bit_cast(half2v, a), bv = __builtin_bit_cast(half2v, b);
  return c + (float)av.x * (float)bv.x + (float)av.y * (float)bv.y;
#endif
}
__device__ __forceinline__ uint alignp(uint a, uint b) {  // {lo:b.hi, hi:a.lo}
  return __builtin_amdgcn_alignbit(a, b, 16);
}
__device__ __forceinline__ unsigned short f2h(float v) {
  return __builtin_bit_cast(unsigned short, (_Float16)v);
}
__device__ __forceinline__ uint getq(const uint4& v, int q) {
  return q == 0 ? v.x : q == 1 ? v.y : q == 2 ? v.z : v.w;
}

// ---- kernel 0: fp32 -> f16 streaming convert
__global__ __launch_bounds__(256) void cvt_f32_f16(const float* __restrict__ x,
                                                   unsigned short* __restrict__ xh,
                                                   int n4) {
  const int stride = gridDim.x * blockDim.x;
  for (int i = blockIdx.x * blockDim.x + threadIdx.x; i < n4; i += stride) {
    const float4 v = *reinterpret_cast<const float4*>(x + (size_t)i * 4);
    uint2 u; u.x = pkrtz(v.x, v.y); u.y = pkrtz(v.z, v.w);
    *reinterpret_cast<uint2*>(xh + (size_t)i * 4) = u;
  }
}

// ---- kernel 0b: pack g into TAP-CONTIGUOUS f16 j-pair tiles.
// uint4 index: (((b*5 + i)*HH + h)*64 + wq)*9 + p   (wq = w/4, p = k*3+jp)
// value.q = {f16 g[(i*5+2jp)*3+k](h,4wq+q), f16 g[(i*5+2jp+1)*3+k](h,4wq+q)|0}
__global__ __launch_bounds__(256) void gpack(const float* __restrict__ g,
                                             uint4* __restrict__ gbuf) {
  const int n = (int)(GPB_UINTS / 4);     // total uint4 items
  const int stride = gridDim.x * blockDim.x;
  for (int it = blockIdx.x * blockDim.x + threadIdx.x; it < n; it += stride) {
    const int p  = it % 9;
    const int wq = (it / 9) & 63;
    const int h  = (it / (9 * 64)) % HH;
    const int bi = it / (9 * 64 * HH);    // b*5 + i
    const int i = bi % 5, b = bi / 5;
    const int k = p / 3, jp = p % 3;
    const int chA = (i * 5 + 2 * jp) * 3 + k;
    const float* gb = g + (size_t)b * GG * PLANE + h * WW + 4 * wq;
    const float4 a = *reinterpret_cast<const float4*>(gb + (size_t)chA * PLANE);
    float4 bq = make_float4(0.f, 0.f, 0.f, 0.f);
    if (jp < 2)
      bq = *reinterpret_cast<const float4*>(gb + (size_t)(chA + 3) * PLANE);
    uint4 u;
    u.x = pkrtz(a.x, bq.x); u.y = pkrtz(a.y, bq.y);
    u.z = pkrtz(a.z, bq.z); u.w = pkrtz(a.w, bq.w);
    gbuf[it] = u;
  }
}

// ---- the aggregation pass: f16 input, OT output (f16 or f32)
template <typename OT, bool PACKED>
__global__ __launch_bounds__(256) void lga_pass(const unsigned short* __restrict__ x,
                                                const float* __restrict__ g,
                                                const uint4* __restrict__ gpk,
                                                OT* __restrict__ out) {
  // XCD-bijective swizzle; dch fastest, then h, c, b.
  constexpr int NWG = BB * CC * NCH * HH;   // 8192
  const int bx = blockIdx.x;
  const int lid = (bx & 7) * (NWG >> 3) + (bx >> 3);
  const int dch = lid % NCH;
  const int h   = (lid / NCH) % HH;
  const int c   = (lid / (NCH * HH)) % CC;
  const int b   =  lid / (NCH * HH * CC);

  const int tid = threadIdx.x;
  const int lane = tid & 63;
  const int dg = tid >> 6;                  // wave index (uniform)
  const int w0 = lane * WPT;
  const int d0 = dch * DCHUNK + dg * DPG;

  const unsigned short* xb = x + (size_t)(b * CC + c) * DD * PLANE;
  const float* gb = g + (size_t)b * GG * PLANE;

  // bpermute byte indices (hoisted)
  const int lm1 = ((lane - 1) & 63) * 4;
  const int lp1 = ((lane + 1) & 63) * 4;
  const bool l0 = (lane == 0);
  const bool l63 = (lane == 63);

  float acc[DPG][WPT];
#pragma unroll
  for (int a = 0; a < DPG; ++a)
#pragma unroll
    for (int q = 0; q < WPT; ++q) acc[a][q] = 0.f;

  const int ilo = (h >= RAD) ? 0 : RAD - h;
  const int him = HH - 1 + RAD - h;
  const int ihi = (him < 4) ? him : 4;

  for (int ii = ilo; ii <= ihi; ++ii) {
    const int hr = h + ii - RAD;

    // G[9]: 144 contiguous bytes per lane (1 base + imm offsets)
    uint4 G[9];
    if constexpr (PACKED) {
      const uint4* gp = gpk + ((size_t)((b * 5 + ii) * HH + h) * 64 + lane) * 9;
#pragma unroll
      for (int p = 0; p < 9; ++p) G[p] = gp[p];
    } else {
#pragma unroll
      for (int k = 0; k < 3; ++k)
#pragma unroll
        for (int jp = 0; jp < 3; ++jp) {
          const int chA = (ii * 5 + 2 * jp) * 3 + k;
          const float4 a = *reinterpret_cast<const float4*>(
              gb + (size_t)chA * PLANE + h * WW + w0);
          float4 bq = make_float4(0.f, 0.f, 0.f, 0.f);
          if (jp < 2)
            bq = *reinterpret_cast<const float4*>(
                gb + (size_t)(chA + 3) * PLANE + h * WW + w0);
          uint4 u;
          u.x = pkrtz(a.x, bq.x); u.y = pkrtz(a.y, bq.y);
          u.z = pkrtz(a.z, bq.z); u.w = pkrtz(a.w, bq.w);
          G[k * 3 + jp] = u;
        }
    }

#pragma unroll
    for (int a = -1; a <= DPG; ++a) {       // x depth rows d0-1 .. d0+6
      bool dok = true;
      if (a == -1)  dok = (d0 > 0);         // wave-uniform depth zero-pad
      if (a == DPG) dok = (d0 + DPG < DD);

      uint2 own = make_uint2(0u, 0u);       // 4 halves: w0 .. w0+3
      if (dok)
        own = *reinterpret_cast<const uint2*>(
            xb + (size_t)(d0 + a) * PLANE + hr * WW + w0);

      // 9-uint window P[m] = {w0-2+2m, w0-1+2m} via cross-lane shuffle
      const uint lft = __builtin_amdgcn_ds_bpermute(lm1, (int)own.y);
      const uint rg0 = __builtin_amdgcn_ds_bpermute(lp1, (int)own.x);
      const uint rg1 = __builtin_amdgcn_ds_bpermute(lp1, (int)own.y);
      uint P[9];
      P[0] = l0 ? 0u : lft;                 // {w0-2, w0-1}
      P[2] = own.x; P[4] = own.y;
      P[6] = l63 ? 0u : rg0;                // {w0+4, w0+5}
      P[8] = l63 ? 0u : rg1;                // {w0+6, w0+7} (x*G_pad0 only)
      P[1] = alignp(P[2], P[0]);
      P[3] = alignp(P[4], P[2]);
      P[5] = alignp(P[6], P[4]);
      P[7] = alignp(P[8], P[6]);

      // scatter: x row d0+a feeds acc[a+1-k]; per (k,ai,q): 3 dot2
#pragma unroll
      for (int k = 0; k < 3; ++k) {
        const int ai = a + 1 - k;
        if (ai < 0 || ai >= DPG) continue;  // compile-time
#pragma unroll
        for (int q = 0; q < WPT; ++q) {
          float t = acc[ai][q];
          t = fdot2(getq(G[k * 3 + 0], q), P[q], t);
          t = fdot2(getq(G[k * 3 + 1], q), P[q + 2], t);
          t = fdot2(getq(G[k * 3 + 2], q), P[q + 4], t);
          acc[ai][q] = t;
        }
      }
    }
  }

  const int obase = d0 * PLANE + h * WW + w0;
  if constexpr (sizeof(OT) == 4) {
    float* ob = (float*)out + (size_t)(b * CC + c) * DD * PLANE;
#pragma unroll
    for (int ai = 0; ai < DPG; ++ai) {
      float4 t; t.x = acc[ai][0]; t.y = acc[ai][1]; t.z = acc[ai][2]; t.w = acc[ai][3];
      *reinterpret_cast<float4*>(ob + obase + ai * PLANE) = t;
    }
  } else {
    unsigned short* ob = (unsigned short*)out + (size_t)(b * CC + c) * DD * PLANE;
#pragma unroll
    for (int ai = 0; ai < DPG; ++ai) {
      ushort4 t; t.x = f2h(acc[ai][0]); t.y = f2h(acc[ai][1]);
      t.z = f2h(acc[ai][2]); t.w = f2h(acc[ai][3]);
      *reinterpret_cast<ushort4*>(ob + obase + ai * PLANE) = t;
    }
  }
}

extern "C" void kernel_launch(void* const* d_in, const int* in_sizes, int n_in,
                              void* d_out, int out_size, void* d_ws, size_t ws_size,
                              hipStream_t stream) {
  const float* x = (const float*)d_in[0];
  const float* g = (const float*)d_in[1];
  float* out = (float*)d_out;

  const size_t elems = (size_t)BB * CC * DD * HH * WW;   // 50,331,648
  // xh (f16) borrows d_out's first 100.6MB; y (f16) at d_ws start.
  // Pass2 reads only d_ws (y + gpk) and overwrites d_out.
  unsigned short* xh = (unsigned short*)d_out;
  unsigned short* y  = (unsigned short*)d_ws;

  cvt_f32_f16<<<2048, 256, 0, stream>>>(x, xh, (int)(elems / 4));

  const dim3 grid(BB * CC * NCH * HH);   // 8192
  const dim3 block(64 * NWV);            // 256

  // Packed-G buffer lives after y in d_ws if it fits (y:100.6MB + gpk:11.8MB).
  const size_t need = elems * 2 + GPB_UINTS * 4;
  if (ws_size >= need) {
    uint4* gbuf = (uint4*)((char*)d_ws + elems * 2);
    gpack<<<1440, 256, 0, stream>>>(g, gbuf);
    lga_pass<unsigned short, true><<<grid, block, 0, stream>>>(xh, g, gbuf, y);
    lga_pass<float, true><<<grid, block, 0, stream>>>(y, g, gbuf, out);
  } else {
    lga_pass<unsigned short, false><<<grid, block, 0, stream>>>(xh, g, nullptr, y);
    lga_pass<float, false><<<grid, block, 0, stream>>>(y, g, nullptr, out);
  }
}